// Round 4
// baseline (234.716 us; speedup 1.0000x reference)
//
#include <hip/hip_runtime.h>

// AWQ int4 GEMM: out[64,11008](f32) = x[64,4096](f32) @ dequant(qweight) + bias
// qweight [K, N/8] int32 AWQ nibble order; qzeros [G, N/8]; scales [G, N] f32; group 128.
//
// Structure (round 4):
//  - convert_x: x f32 -> bf16 into d_ws (512 KB) once per call.
//  - init_out: out = bias.
//  - awq_gemm: BN=128, split-K=8, atomicAdd epilogue.
//    Interleaved-n fragment mapping: fragment (wave w, f) covers
//      n = nb*128 + l15*8 + c,  c = 2*w + f  (c = logical col within pack)
//    so a quad's 16 lanes read 16 CONSECUTIVE qweight dwords per k-row
//    (fully coalesced, each 64B line fully consumed by the block), and the
//    8 dword loads per k-step serve both fragments (different nibbles).

#define KD   4096
#define ND   11008
#define NPW  1376      // ND/8
#define BN   128       // n-columns per block (16 packed dwords = one 64B line/row)
#define KS   8         // split-K factor
#define KCH  (KD / KS) // 512 = 4 quant groups

using frag_ab = __attribute__((ext_vector_type(8))) short;   // 8 bf16 = 4 VGPR
using f32x4   = __attribute__((ext_vector_type(4))) float;
using bf16x8  = __attribute__((ext_vector_type(8))) __bf16;
using bf16x4  = __attribute__((ext_vector_type(4))) __bf16;

// ---- x f32 -> bf16 (64*4096 = 262144 elements, 4 per thread) ----
__global__ __launch_bounds__(256) void convert_x(
    const float* __restrict__ x, __bf16* __restrict__ xb)
{
    const int i = (blockIdx.x * 256 + threadIdx.x) * 4;
    const f32x4 v = *(const f32x4*)(x + i);
    bf16x4 r;
    r[0] = (__bf16)v[0]; r[1] = (__bf16)v[1];
    r[2] = (__bf16)v[2]; r[3] = (__bf16)v[3];
    *(bf16x4*)(xb + i) = r;
}

// ---- out[m, n] = bias[n]  (ND = 43*256) ----
__global__ __launch_bounds__(256) void init_out(
    const float* __restrict__ bias, float* __restrict__ out)
{
    const int n = blockIdx.x * 256 + threadIdx.x;
    out[blockIdx.y * ND + n] = bias[n];
}

__global__ __launch_bounds__(256, 3) void awq_gemm(
    const __bf16* __restrict__ xb,
    const int*    __restrict__ qw,
    const float*  __restrict__ sc,
    const int*    __restrict__ qz,
    float*        __restrict__ out)
{
    const int tid  = threadIdx.x;
    const int wv   = tid >> 6;        // wave 0..3
    const int lane = tid & 63;
    const int l15  = lane & 15;
    const int q4   = lane >> 4;       // quad 0..3

    const int nb  = blockIdx.x;
    const int npw = nb * 16 + l15;    // this lane's packed dword column

    // fragment nibble (logical col within pack): c0 = 2*wv, c1 = 2*wv+1
    const int c0  = wv * 2;
    // AWQ: logical col c sits at nibble ((c&1)<<2)|(c>>1)
    const int sh0 = ((((c0 & 1) << 2) | (c0 >> 1)) << 2);
    const int c1  = c0 + 1;
    const int sh1 = ((((c1 & 1) << 2) | (c1 >> 1)) << 2);

    const int n0  = nb * BN + l15 * 8 + c0;   // this lane's first output column

    const int k_start = blockIdx.y * KCH;
    const int k_end   = k_start + KCH;

    const int*    qwp = qw + npw;             // row k at qwp[k*NPW]
    const __bf16* xp  = xb + l15 * KD;        // + mt*16*KD + k

    f32x4 acc[2][4] = {};   // [frag][m-tile]

    // ---- software-pipelined k loop (one step of prefetch) ----
    int     w_pf[8];
    frag_ab a_pf[4];
    {
        const int kb = k_start + q4 * 8;
        #pragma unroll
        for (int j = 0; j < 8; ++j) w_pf[j] = qwp[(kb + j) * NPW];
        #pragma unroll
        for (int mt = 0; mt < 4; ++mt)
            a_pf[mt] = *(const frag_ab*)(xp + mt * 16 * KD + kb);
    }

    float s0 = 0.f, z0 = 0.f, s1 = 0.f, z1 = 0.f;
    for (int k0 = k_start; k0 < k_end; k0 += 32) {
        // group scale/zero (uniform branch, every 4th iteration)
        if ((k0 & 127) == 0) {
            const int g  = k0 >> 7;
            const int zw = qz[g * NPW + npw];
            s0 = sc[g * ND + n0];
            s1 = sc[g * ND + n0 + 1];
            z0 = -s0 * (float)((zw >> sh0) & 0xF);   // exact in f32
            z1 = -s1 * (float)((zw >> sh1) & 0xF);
        }

        // take current stage
        int     w_c[8];
        frag_ab a_c[4];
        #pragma unroll
        for (int j = 0; j < 8; ++j)  w_c[j]  = w_pf[j];
        #pragma unroll
        for (int mt = 0; mt < 4; ++mt) a_c[mt] = a_pf[mt];

        // prefetch next k-step
        const int k1 = k0 + 32;
        if (k1 < k_end) {
            const int kb = k1 + q4 * 8;
            #pragma unroll
            for (int j = 0; j < 8; ++j) w_pf[j] = qwp[(kb + j) * NPW];
            #pragma unroll
            for (int mt = 0; mt < 4; ++mt)
                a_pf[mt] = *(const frag_ab*)(xp + mt * 16 * KD + kb);
        }

        // dequant both fragments from the same 8 dwords
        bf16x8 bb0, bb1;
        #pragma unroll
        for (int j = 0; j < 8; ++j) {
            const int w = w_c[j];
            bb0[j] = (__bf16)fmaf((float)((w >> sh0) & 0xF), s0, z0);
            bb1[j] = (__bf16)fmaf((float)((w >> sh1) & 0xF), s1, z1);
        }
        const frag_ab b0 = __builtin_bit_cast(frag_ab, bb0);
        const frag_ab b1 = __builtin_bit_cast(frag_ab, bb1);

        #pragma unroll
        for (int mt = 0; mt < 4; ++mt) {
            acc[0][mt] = __builtin_amdgcn_mfma_f32_16x16x32_bf16(a_c[mt], b0, acc[0][mt], 0, 0, 0);
            acc[1][mt] = __builtin_amdgcn_mfma_f32_16x16x32_bf16(a_c[mt], b1, acc[1][mt], 0, 0, 0);
        }
    }

    // ---- epilogue: C/D col = l15 (our n-index), row = q4*4 + r ----
    #pragma unroll
    for (int mt = 0; mt < 4; ++mt) {
        #pragma unroll
        for (int r = 0; r < 4; ++r) {
            const int m = mt * 16 + q4 * 4 + r;
            atomicAdd(&out[m * ND + n0],     acc[0][mt][r]);
            atomicAdd(&out[m * ND + n0 + 1], acc[1][mt][r]);
        }
    }
}

extern "C" void kernel_launch(void* const* d_in, const int* in_sizes, int n_in,
                              void* d_out, int out_size, void* d_ws, size_t ws_size,
                              hipStream_t stream) {
    const float* x    = (const float*)d_in[0];
    const int*   qw   = (const int*)d_in[1];
    const float* sc   = (const float*)d_in[2];
    const int*   qz   = (const int*)d_in[3];
    const float* bias = (const float*)d_in[4];
    float*       out  = (float*)d_out;
    __bf16*      xb   = (__bf16*)d_ws;        // 64*4096*2 = 512 KB scratch

    convert_x<<<dim3(64 * KD / (256 * 4)), 256, 0, stream>>>(x, xb);
    init_out<<<dim3(ND / 256, 64), 256, 0, stream>>>(bias, out);
    awq_gemm<<<dim3(ND / BN, KS), 256, 0, stream>>>(xb, qw, sc, qz, out);
}

// Round 5
// 110.961 us; speedup vs baseline: 2.1153x; 2.1153x over previous
//
#include <hip/hip_runtime.h>

// AWQ int4 GEMM: out[64,11008](f32) = x[64,4096](f32) @ dequant(qweight) + bias
// qweight [K, N/8] int32 AWQ nibble order; qzeros [G, N/8]; scales [G, N] f32; group 128.
//
// Round 5 structure:
//  - convert_x: x f32 -> bf16 into d_ws[0 .. 512KB).
//  - awq_gemm: BN=128, split-K=8. Partials -> d_ws (plain coalescable stores,
//    NO atomics: round-4 atomics caused 172 MB of HBM write traffic).
//  - reduce_out: out = bias + sum of 8 partials.
//  Interleaved-n fragment mapping: fragment (wave w, f) covers
//    n = nb*128 + l15*8 + c, c = 2*w + f, so a quad's 16 lanes read 16
//    CONSECUTIVE qweight dwords per k-row (fully coalesced) and the 8 dwords
//    per k-step serve both of the wave's fragments.

#define KD   4096
#define ND   11008
#define NPW  1376      // ND/8
#define BN   128       // n-columns per block (16 packed dwords = one 64B line/row)
#define KS   8         // split-K factor
#define KCH  (KD / KS) // 512 = 4 quant groups
#define MD   64        // rows of x / out

using frag_ab = __attribute__((ext_vector_type(8))) short;   // 8 bf16 = 4 VGPR
using f32x4   = __attribute__((ext_vector_type(4))) float;
using bf16x8  = __attribute__((ext_vector_type(8))) __bf16;
using bf16x4  = __attribute__((ext_vector_type(4))) __bf16;

// ---- x f32 -> bf16 (64*4096 = 262144 elements, 4 per thread) ----
__global__ __launch_bounds__(256) void convert_x(
    const float* __restrict__ x, __bf16* __restrict__ xb)
{
    const int i = (blockIdx.x * 256 + threadIdx.x) * 4;
    const f32x4 v = *(const f32x4*)(x + i);
    bf16x4 r;
    r[0] = (__bf16)v[0]; r[1] = (__bf16)v[1];
    r[2] = (__bf16)v[2]; r[3] = (__bf16)v[3];
    *(bf16x4*)(xb + i) = r;
}

__global__ __launch_bounds__(256) void awq_gemm(
    const __bf16* __restrict__ xb,
    const int*    __restrict__ qw,
    const float*  __restrict__ sc,
    const int*    __restrict__ qz,
    float*        __restrict__ part)   // [KS][MD][ND]
{
    const int tid  = threadIdx.x;
    const int wv   = tid >> 6;        // wave 0..3
    const int lane = tid & 63;
    const int l15  = lane & 15;
    const int q4   = lane >> 4;       // quad 0..3

    const int nb  = blockIdx.x;
    const int npw = nb * 16 + l15;    // this lane's packed dword column

    // fragment nibble (logical col within pack): c0 = 2*wv, c1 = 2*wv+1
    const int c0  = wv * 2;
    // AWQ: logical col c sits at nibble ((c&1)<<2)|(c>>1)
    const int sh0 = ((((c0 & 1) << 2) | (c0 >> 1)) << 2);
    const int c1  = c0 + 1;
    const int sh1 = ((((c1 & 1) << 2) | (c1 >> 1)) << 2);

    const int n0  = nb * BN + l15 * 8 + c0;   // this lane's first output column

    const int k_start = blockIdx.y * KCH;
    const int k_end   = k_start + KCH;

    const int*    qwp = qw + npw;             // row k at qwp[k*NPW]
    const __bf16* xp  = xb + l15 * KD;        // + mt*16*KD + k

    f32x4 acc[2][4] = {};   // [frag][m-tile]

    // ---- software-pipelined k loop (one step of prefetch) ----
    int     w_pf[8];
    frag_ab a_pf[4];
    {
        const int kb = k_start + q4 * 8;
        #pragma unroll
        for (int j = 0; j < 8; ++j) w_pf[j] = qwp[(kb + j) * NPW];
        #pragma unroll
        for (int mt = 0; mt < 4; ++mt)
            a_pf[mt] = *(const frag_ab*)(xp + mt * 16 * KD + kb);
    }

    float s0 = 0.f, z0 = 0.f, s1 = 0.f, z1 = 0.f;
    for (int k0 = k_start; k0 < k_end; k0 += 32) {
        // group scale/zero (uniform branch, every 4th iteration)
        if ((k0 & 127) == 0) {
            const int g  = k0 >> 7;
            const int zw = qz[g * NPW + npw];
            s0 = sc[g * ND + n0];
            s1 = sc[g * ND + n0 + 1];
            z0 = -s0 * (float)((zw >> sh0) & 0xF);   // exact in f32
            z1 = -s1 * (float)((zw >> sh1) & 0xF);
        }

        // take current stage
        int     w_c[8];
        frag_ab a_c[4];
        #pragma unroll
        for (int j = 0; j < 8; ++j)  w_c[j]  = w_pf[j];
        #pragma unroll
        for (int mt = 0; mt < 4; ++mt) a_c[mt] = a_pf[mt];

        // prefetch next k-step
        const int k1 = k0 + 32;
        if (k1 < k_end) {
            const int kb = k1 + q4 * 8;
            #pragma unroll
            for (int j = 0; j < 8; ++j) w_pf[j] = qwp[(kb + j) * NPW];
            #pragma unroll
            for (int mt = 0; mt < 4; ++mt)
                a_pf[mt] = *(const frag_ab*)(xp + mt * 16 * KD + kb);
        }

        // dequant both fragments from the same 8 dwords
        bf16x8 bb0, bb1;
        #pragma unroll
        for (int j = 0; j < 8; ++j) {
            const int w = w_c[j];
            bb0[j] = (__bf16)fmaf((float)((w >> sh0) & 0xF), s0, z0);
            bb1[j] = (__bf16)fmaf((float)((w >> sh1) & 0xF), s1, z1);
        }
        const frag_ab b0 = __builtin_bit_cast(frag_ab, bb0);
        const frag_ab b1 = __builtin_bit_cast(frag_ab, bb1);

        #pragma unroll
        for (int mt = 0; mt < 4; ++mt) {
            acc[0][mt] = __builtin_amdgcn_mfma_f32_16x16x32_bf16(a_c[mt], b0, acc[0][mt], 0, 0, 0);
            acc[1][mt] = __builtin_amdgcn_mfma_f32_16x16x32_bf16(a_c[mt], b1, acc[1][mt], 0, 0, 0);
        }
    }

    // ---- epilogue: plain stores to the split-K partial buffer ----
    // C/D layout: col = l15 (our n index), row = q4*4 + r
    float* pp = part + blockIdx.y * (MD * ND);
    #pragma unroll
    for (int mt = 0; mt < 4; ++mt) {
        #pragma unroll
        for (int r = 0; r < 4; ++r) {
            const int m = mt * 16 + q4 * 4 + r;
            *(float2*)(pp + m * ND + n0) = make_float2(acc[0][mt][r], acc[1][mt][r]);
        }
    }
}

// ---- out[m,n] = bias[n] + sum_ks part[ks][m][n];  grid (ND/256, MD) ----
__global__ __launch_bounds__(256) void reduce_out(
    const float* __restrict__ part,
    const float* __restrict__ bias,
    float*       __restrict__ out)
{
    const int n = blockIdx.x * 256 + threadIdx.x;
    const int m = blockIdx.y;
    float s = bias[n];
    #pragma unroll
    for (int ks = 0; ks < KS; ++ks)
        s += part[ks * (MD * ND) + m * ND + n];
    out[m * ND + n] = s;
}

extern "C" void kernel_launch(void* const* d_in, const int* in_sizes, int n_in,
                              void* d_out, int out_size, void* d_ws, size_t ws_size,
                              hipStream_t stream) {
    const float* x    = (const float*)d_in[0];
    const int*   qw   = (const int*)d_in[1];
    const float* sc   = (const float*)d_in[2];
    const int*   qz   = (const int*)d_in[3];
    const float* bias = (const float*)d_in[4];
    float*       out  = (float*)d_out;

    __bf16* xb   = (__bf16*)d_ws;                         // 512 KB
    float*  part = (float*)((char*)d_ws + MD * KD * 2);   // KS*MD*ND*4 = 22.5 MB

    convert_x<<<dim3(MD * KD / (256 * 4)), 256, 0, stream>>>(x, xb);
    awq_gemm<<<dim3(ND / BN, KS), 256, 0, stream>>>(xb, qw, sc, qz, part);
    reduce_out<<<dim3(ND / 256, MD), 256, 0, stream>>>(part, bias, out);
}